// Round 11
// baseline (337.054 us; speedup 1.0000x reference)
//
#include <hip/hip_runtime.h>
#include <hip/hip_bf16.h>

#define Bn 2
#define Sn 4096
#define Dn 512
#define Hn 8

typedef _Float16 f16x8 __attribute__((ext_vector_type(8)));
typedef __fp16 fp16x2 __attribute__((ext_vector_type(2)));
typedef float f32x16 __attribute__((ext_vector_type(16)));
typedef unsigned uint2v __attribute__((ext_vector_type(2)));

#if __has_builtin(__builtin_amdgcn_global_load_lds)
#define HAS_GLL 1
typedef const __attribute__((address_space(1))) unsigned int* gas1_t;
typedef __attribute__((address_space(3))) unsigned int* las3_t;
// async 16B/lane global->LDS: LDS dst = uniform base + lane*16
static __device__ __forceinline__ void ld_lds16(const void* g, void* l) {
    __builtin_amdgcn_global_load_lds((gas1_t)g, (las3_t)l, 16, 0, 0);
}
#else
#define HAS_GLL 0
#endif

// pack two f32 -> two f16 in one dword (v_cvt_pkrtz_f16_f32, 1 VALU op)
static __device__ __forceinline__ unsigned pkh(float a, float b) {
    union { fp16x2 h; unsigned u; } r;
    r.h = __builtin_amdgcn_cvt_pkrtz(a, b);
    return r.u;
}

// C-layout group pair -> A/B-fragment (K=16 shapes) via lane^32 exchange.
static __device__ __forceinline__ f16x8 xchg2(unsigned g0x, unsigned g0y,
                                              unsigned g1x, unsigned g1y, int hi) {
    union { unsigned u[4]; f16x8 v; } f;
#if __has_builtin(__builtin_amdgcn_permlane32_swap)
    uint2v rx = __builtin_amdgcn_permlane32_swap(g0x, g1x, false, false);
    uint2v ry = __builtin_amdgcn_permlane32_swap(g0y, g1y, false, false);
    f.u[0] = rx.x; f.u[1] = ry.x; f.u[2] = rx.y; f.u[3] = ry.y;
#else
    int sx = hi ? (int)g0x : (int)g1x;
    int sy = hi ? (int)g0y : (int)g1y;
    int rx = __shfl_xor(sx, 32);
    int ry = __shfl_xor(sy, 32);
    unsigned ox = hi ? g1x : g0x;
    unsigned oy = hi ? g1y : g0y;
    f.u[0] = hi ? (unsigned)rx : ox;
    f.u[1] = hi ? (unsigned)ry : oy;
    f.u[2] = hi ? ox : (unsigned)rx;
    f.u[3] = hi ? oy : (unsigned)ry;
#endif
    return f.v;
}

// ---------- unified prepass: K,V,W fp32 -> fragment-ordered f16 ----------
__global__ __launch_bounds__(256) void prep_kernel(
    const float* __restrict__ K, const float* __restrict__ V, const float* __restrict__ W,
    unsigned short* __restrict__ Kb, unsigned short* __restrict__ Vb,
    unsigned short* __restrict__ Wb) {
    const int vb = blockIdx.x;
    const int tid = threadIdx.x;
    if (vb < 1024) {
        const int kt = vb & 63, bh = vb >> 6;
        const int b = bh >> 3, h = bh & 7;
        unsigned short* dst = Kb + ((size_t)bh * 64 + kt) * 4096;
#pragma unroll
        for (int i = 0; i < 2; ++i) {
            int c = tid + i * 256;
            int f = c >> 6, ln = c & 63;
            int ktile = f >> 2, ks = f & 3;
            int row = ktile * 32 + (ln & 31);
            int dk = ks * 16 + (ln >> 5) * 8;
            const float* src = K + ((size_t)(b * Sn + kt * 64 + row)) * Dn + h * 64 + dk;
            float4 a0 = *(const float4*)src;
            float4 a1 = *(const float4*)(src + 4);
            uint4 o;
            o.x = pkh(a0.x, a0.y); o.y = pkh(a0.z, a0.w);
            o.z = pkh(a1.x, a1.y); o.w = pkh(a1.z, a1.w);
            *(uint4*)(dst + c * 8) = o;
        }
    } else if (vb < 2048) {
        const int u = vb - 1024;
        const int kt = u & 63, bh = u >> 6;
        const int b = bh >> 3, h = bh & 7;
        unsigned short* dst = Vb + ((size_t)bh * 64 + kt) * 4096;
#pragma unroll
        for (int i = 0; i < 2; ++i) {
            int c = tid + i * 256;
            int f = c >> 6, ln = c & 63;
            int dt = f >> 2, ks = f & 3;
            int dk = dt * 32 + (ln & 31);
            int key0 = ks * 16 + (ln >> 5) * 8;
            const float* src = V + ((size_t)(b * Sn + kt * 64 + key0)) * Dn + h * 64 + dk;
            uint4 o;
            o.x = pkh(src[0 * Dn], src[1 * Dn]);
            o.y = pkh(src[2 * Dn], src[3 * Dn]);
            o.z = pkh(src[4 * Dn], src[5 * Dn]);
            o.w = pkh(src[6 * Dn], src[7 * Dn]);
            *(uint4*)(dst + c * 8) = o;
        }
    } else {
        int c = (vb - 2048) * 256 + tid;
        int ln = c & 63, f = c >> 6;
        int ntile = f >> 5, ks = f & 31;
        int n = ntile * 32 + (ln & 31);
        int k0 = ks * 16 + (ln >> 5) * 8;
        uint4 o;
        o.x = pkh(W[(size_t)(k0 + 0) * Dn + n], W[(size_t)(k0 + 1) * Dn + n]);
        o.y = pkh(W[(size_t)(k0 + 2) * Dn + n], W[(size_t)(k0 + 3) * Dn + n]);
        o.z = pkh(W[(size_t)(k0 + 4) * Dn + n], W[(size_t)(k0 + 5) * Dn + n]);
        o.w = pkh(W[(size_t)(k0 + 6) * Dn + n], W[(size_t)(k0 + 7) * Dn + n]);
        *(uint4*)(Wb + c * 8) = o;
    }
}

// ---------- flash attention: BARRIER-FREE main loop (private per-wave LDS) ----------
// 10-round invariant: MfmaUtil*dur ~ const -> the per-tile __syncthreads convoy
// phase-locks all waves (MFMA blocks its wave; only other-wave work can overlap;
// barrier re-locks every tile). Fix: vmcnt is PER-WAVE, so a wave staging its
// OWN 8KB LDS slice via global_load_lds needs only s_waitcnt vmcnt(0) - zero
// barriers. 1024 blocks x 4 waves; wave kg: 64 q-rows x private 1024-key
// quarter, 32 iters x 32-key chunks, 16 MFMA / 8KB per iter. LDS 32KB/block ->
// 4 blocks/CU -> 16 waves/CU, each SIMD: 4 phase-free waves (cross-wave
// MFMA/VALU/vmcnt overlap unconstrained). Barriers only in the kg-reduce
// epilogue. XCD swizzle: 2 bh/XCD -> K/V L2-resident.
__global__ __launch_bounds__(256, 4) void attn_kernel(
    const float* __restrict__ Q,
    const unsigned short* __restrict__ Kb,
    const unsigned short* __restrict__ Vb,
    unsigned short* __restrict__ ObA) {   // [gmtile 256][ksg 32][lane 64][8]
    // [wave 4][ K 4 frags | V 4 frags ] x 512 ushorts = 32 KB
    // epilogue reuse: 6144 floats oacc partials + 192 floats l = 25344 B
    __shared__ __align__(16) unsigned short KV[16384];

    // XCD-aware remap: id%8 -> XCD (round-robin dispatch); 2 bh per XCD residue
    const int id = blockIdx.x + (blockIdx.y << 6);
    const int qt = (id >> 3) & 63;                  // 64-row q-tile
    const int bh = (id & 7) + ((id >> 9) << 3);
    const int b = bh >> 3, h = bh & 7;
    const int tid = threadIdx.x;
    const int kg = tid >> 6;       // key quarter 0..3 (= wave id)
    const int lane = tid & 63;
    const int q = lane & 31;
    const int hi = lane >> 5;
    const float cexp = 0.18033688f;  // (1/sqrt(64)) * log2(e), folded into Q

    // Q B-frags for two q-tiles: rows qt*64 + t*32 + q
    f16x8 qf0[4], qf1[4];
    {
        const float* qp0 = Q + ((size_t)(b * Sn + qt * 64 + q)) * Dn + h * 64 + hi * 8;
        const float* qp1 = qp0 + (size_t)32 * Dn;
#pragma unroll
        for (int ks = 0; ks < 4; ++ks) {
            float4 a0 = *(const float4*)(qp0 + ks * 16);
            float4 a1 = *(const float4*)(qp0 + ks * 16 + 4);
            union { unsigned u[4]; f16x8 v; } f;
            f.u[0] = pkh(a0.x * cexp, a0.y * cexp);
            f.u[1] = pkh(a0.z * cexp, a0.w * cexp);
            f.u[2] = pkh(a1.x * cexp, a1.y * cexp);
            f.u[3] = pkh(a1.z * cexp, a1.w * cexp);
            qf0[ks] = f.v;
            a0 = *(const float4*)(qp1 + ks * 16);
            a1 = *(const float4*)(qp1 + ks * 16 + 4);
            f.u[0] = pkh(a0.x * cexp, a0.y * cexp);
            f.u[1] = pkh(a0.z * cexp, a0.w * cexp);
            f.u[2] = pkh(a1.x * cexp, a1.y * cexp);
            f.u[3] = pkh(a1.z * cexp, a1.w * cexp);
            qf1[ks] = f.v;
        }
    }

    f32x16 zf;
#pragma unroll
    for (int r = 0; r < 16; ++r) zf[r] = 0.f;
    f32x16 oacc[2][2];  // [q-tile t][d-tile dt]
    oacc[0][0] = zf; oacc[0][1] = zf; oacc[1][0] = zf; oacc[1][1] = zf;
    float l0_ = 0.f, l1_ = 0.f;

    const size_t bhbase = (size_t)bh * 64 * 4096;  // ushorts
    const unsigned short* kB = Kb + bhbase;
    const unsigned short* vB = Vb + bhbase;
    unsigned short* const lb = &KV[kg * 4096];     // private 8KB slice

    for (int it = 0; it < 32; ++it) {
        // stage my 32-key chunk: keys kg*1024 + it*32 .. +31
        const int t64 = kg * 16 + (it >> 1);
        const int lohi = it & 1;
        {
            const unsigned short* ks_ = kB + (size_t)t64 * 4096 + lohi * 2048 + lane * 8;
            const unsigned short* vs_ = vB + (size_t)t64 * 4096 + lohi * 1024 + lane * 8;
#if HAS_GLL
            ld_lds16(ks_, lb);          ld_lds16(ks_ + 512, lb + 512);
            ld_lds16(ks_ + 1024, lb + 1024); ld_lds16(ks_ + 1536, lb + 1536);
            ld_lds16(vs_, lb + 2048);   ld_lds16(vs_ + 512, lb + 2560);
            ld_lds16(vs_ + 2048, lb + 3072); ld_lds16(vs_ + 2560, lb + 3584);
            // per-wave completion fence: my loads only (vmcnt is wave-local) - NO barrier
            asm volatile("s_waitcnt vmcnt(0)" ::: "memory");
#else
            uint4 a0 = *(const uint4*)(ks_);        uint4 a1 = *(const uint4*)(ks_ + 512);
            uint4 a2 = *(const uint4*)(ks_ + 1024); uint4 a3 = *(const uint4*)(ks_ + 1536);
            uint4 b0 = *(const uint4*)(vs_);        uint4 b1 = *(const uint4*)(vs_ + 512);
            uint4 b2 = *(const uint4*)(vs_ + 2048); uint4 b3 = *(const uint4*)(vs_ + 2560);
            *(uint4*)&lb[lane * 8] = a0;        *(uint4*)&lb[512 + lane * 8] = a1;
            *(uint4*)&lb[1024 + lane * 8] = a2; *(uint4*)&lb[1536 + lane * 8] = a3;
            *(uint4*)&lb[2048 + lane * 8] = b0; *(uint4*)&lb[2560 + lane * 8] = b1;
            *(uint4*)&lb[3072 + lane * 8] = b2; *(uint4*)&lb[3584 + lane * 8] = b3;
            asm volatile("s_waitcnt lgkmcnt(0)" ::: "memory");
#endif
#if __has_builtin(__builtin_amdgcn_sched_barrier)
            __builtin_amdgcn_sched_barrier(0);
#endif
        }

        // QK: one K-frag read feeds both q-tiles' MFMAs (32-key tile)
        f32x16 sa0, sa1;
        {
            f16x8 kf = *(const f16x8*)&lb[0 * 512 + lane * 8];
            sa0 = __builtin_amdgcn_mfma_f32_32x32x16_f16(kf, qf0[0], zf, 0, 0, 0);
            sa1 = __builtin_amdgcn_mfma_f32_32x32x16_f16(kf, qf1[0], zf, 0, 0, 0);
#pragma unroll
            for (int ks = 1; ks < 4; ++ks) {
                kf = *(const f16x8*)&lb[ks * 512 + lane * 8];
                sa0 = __builtin_amdgcn_mfma_f32_32x32x16_f16(kf, qf0[ks], sa0, 0, 0, 0);
                sa1 = __builtin_amdgcn_mfma_f32_32x32x16_f16(kf, qf1[ks], sa1, 0, 0, 0);
            }
        }
        // exp2 fused with f16 pack (16 packed dwords live, not 32 floats)
        unsigned u0[8], u1[8];
        float s0 = 0.f, s1 = 0.f;
#pragma unroll
        for (int j = 0; j < 8; ++j) {
            float ea = __builtin_amdgcn_exp2f(sa0[2 * j]);
            float eb = __builtin_amdgcn_exp2f(sa0[2 * j + 1]);
            s0 += ea + eb;
            u0[j] = pkh(ea, eb);
        }
#pragma unroll
        for (int j = 0; j < 8; ++j) {
            float ea = __builtin_amdgcn_exp2f(sa1[2 * j]);
            float eb = __builtin_amdgcn_exp2f(sa1[2 * j + 1]);
            s1 += ea + eb;
            u1[j] = pkh(ea, eb);
        }
        l0_ += s0; l1_ += s1;

        // PV: one V-frag pair feeds both q-tiles (2 k-slots of 16 keys)
#pragma unroll
        for (int ks2 = 0; ks2 < 2; ++ks2) {
            f16x8 pb0 = xchg2(u0[4 * ks2 + 0], u0[4 * ks2 + 1], u0[4 * ks2 + 2], u0[4 * ks2 + 3], hi);
            f16x8 pb1 = xchg2(u1[4 * ks2 + 0], u1[4 * ks2 + 1], u1[4 * ks2 + 2], u1[4 * ks2 + 3], hi);
            f16x8 va0 = *(const f16x8*)&lb[2048 + ks2 * 512 + lane * 8];
            f16x8 va1 = *(const f16x8*)&lb[3072 + ks2 * 512 + lane * 8];
            oacc[0][0] = __builtin_amdgcn_mfma_f32_32x32x16_f16(va0, pb0, oacc[0][0], 0, 0, 0);
            oacc[0][1] = __builtin_amdgcn_mfma_f32_32x32x16_f16(va1, pb0, oacc[0][1], 0, 0, 0);
            oacc[1][0] = __builtin_amdgcn_mfma_f32_32x32x16_f16(va0, pb1, oacc[1][0], 0, 0, 0);
            oacc[1][1] = __builtin_amdgcn_mfma_f32_32x32x16_f16(va1, pb1, oacc[1][1], 0, 0, 0);
        }
    }

    // 4-way kg reduction, 2 phases (one per q-tile t). Per phase: kg1..3 write
    // (3 regions x 2048 floats = 24KB) + l (192 floats); kg0 accumulates.
    __syncthreads();
    float* red = (float*)KV;
#pragma unroll
    for (int t = 0; t < 2; ++t) {
        if (kg != 0) {
            float* rp = red + (kg - 1) * 2048;
#pragma unroll
            for (int dt = 0; dt < 2; ++dt)
#pragma unroll
                for (int g = 0; g < 4; ++g) {
                    float4 v;
                    v.x = oacc[t][dt][g * 4 + 0];
                    v.y = oacc[t][dt][g * 4 + 1];
                    v.z = oacc[t][dt][g * 4 + 2];
                    v.w = oacc[t][dt][g * 4 + 3];
                    *(float4*)&rp[(dt * 4 + g) * 256 + lane * 4] = v;
                }
            red[6144 + (kg - 1) * 64 + lane] = t ? l1_ : l0_;
        }
        __syncthreads();
        if (kg == 0) {
#pragma unroll
            for (int slot = 0; slot < 3; ++slot) {
                float* rp = red + slot * 2048;
#pragma unroll
                for (int dt = 0; dt < 2; ++dt)
#pragma unroll
                    for (int g = 0; g < 4; ++g) {
                        float4 v = *(const float4*)&rp[(dt * 4 + g) * 256 + lane * 4];
                        oacc[t][dt][g * 4 + 0] += v.x;
                        oacc[t][dt][g * 4 + 1] += v.y;
                        oacc[t][dt][g * 4 + 2] += v.z;
                        oacc[t][dt][g * 4 + 3] += v.w;
                    }
                float addl = red[6144 + slot * 64 + lane];
                if (t) l1_ += addl; else l0_ += addl;
            }
        }
        __syncthreads();
    }

    if (kg == 0) {
        l0_ += __shfl_xor(l0_, 32);
        l1_ += __shfl_xor(l1_, 32);
#pragma unroll
        for (int t = 0; t < 2; ++t) {
            const float li = 1.f / (t ? l1_ : l0_);
            const int gm = b * 128 + qt * 2 + t;
#pragma unroll
            for (int ksg = 0; ksg < 4; ++ksg) {
                const int dt = ksg >> 1, k2 = ksg & 1;
                unsigned g0x = pkh(oacc[t][dt][8 * k2 + 0] * li, oacc[t][dt][8 * k2 + 1] * li);
                unsigned g0y = pkh(oacc[t][dt][8 * k2 + 2] * li, oacc[t][dt][8 * k2 + 3] * li);
                unsigned g1x = pkh(oacc[t][dt][8 * k2 + 4] * li, oacc[t][dt][8 * k2 + 5] * li);
                unsigned g1y = pkh(oacc[t][dt][8 * k2 + 6] * li, oacc[t][dt][8 * k2 + 7] * li);
                f16x8 frag = xchg2(g0x, g0y, g1x, g1y, hi);
                union { f16x8 v; uint4 u; } fu; fu.v = frag;
                *(uint4*)&ObA[((size_t)(gm * 32 + h * 4 + ksg) * 64 + lane) * 8] = fu.u;
            }
        }
    }
}

// ---------- projection GEMM: out = A @ W + b (A,W fragment-ordered f16) ----------
__global__ __launch_bounds__(256) void proj_kernel(
    const unsigned short* __restrict__ ObA,  // [256][32][64][8]
    const unsigned short* __restrict__ Wb,   // [16][32][64][8]
    const float* __restrict__ bias,
    float* __restrict__ out) {
    __shared__ __align__(16) unsigned short Ash[8192];
    __shared__ __align__(16) unsigned short Wsh[4096];

    const int mt = blockIdx.x;
    const int nt = blockIdx.y;
    const int tid = threadIdx.x;
    const int w = tid >> 6;
    const int lane = tid & 63;
    const int q = lane & 31;
    const int hi = lane >> 5;

    f32x16 acc[2];
#pragma unroll
    for (int t = 0; t < 2; ++t)
#pragma unroll
        for (int r = 0; r < 16; ++r) acc[t][r] = 0.f;

    for (int kt = 0; kt < 8; ++kt) {
        __syncthreads();
#pragma unroll
        for (int i = 0; i < 4; ++i) {
            int ci = (tid >> 6) + i * 4;
            int ml = ci >> 2, ksl = ci & 3;
            *(uint4*)&Ash[ci * 512 + lane * 8] =
                *(const uint4*)(ObA + (((size_t)(mt * 4 + ml) * 32 + kt * 4 + ksl) * 64 + lane) * 8);
        }
#pragma unroll
        for (int i = 0; i < 2; ++i) {
            int ci = (tid >> 6) + i * 4;
            int ntl = ci >> 2, ksl = ci & 3;
            *(uint4*)&Wsh[ci * 512 + lane * 8] =
                *(const uint4*)(Wb + (((size_t)(nt * 2 + ntl) * 32 + kt * 4 + ksl) * 64 + lane) * 8);
        }
        __syncthreads();

#pragma unroll
        for (int ks = 0; ks < 4; ++ks) {
            f16x8 a  = *(const f16x8*)&Ash[(w * 4 + ks) * 512 + lane * 8];
            f16x8 b0 = *(const f16x8*)&Wsh[(0 * 4 + ks) * 512 + lane * 8];
            f16x8 b1 = *(const f16x8*)&Wsh[(4 + ks) * 512 + lane * 8];
            acc[0] = __builtin_amdgcn_mfma_f32_32x32x16_f16(a, b0, acc[0], 0, 0, 0);
            acc[1] = __builtin_amdgcn_mfma_f32_32x32x16_f16(a, b1, acc[1], 0, 0, 0);
        }
    }

#pragma unroll
    for (int ntl = 0; ntl < 2; ++ntl) {
        int col = nt * 64 + ntl * 32 + q;
        float bv = bias[col];
#pragma unroll
        for (int reg = 0; reg < 16; ++reg) {
            int row = mt * 128 + w * 32 + (reg & 3) + 8 * (reg >> 2) + 4 * hi;
            out[(size_t)row * Dn + col] = acc[ntl][reg] + bv;
        }
    }
}

extern "C" void kernel_launch(void* const* d_in, const int* in_sizes, int n_in,
                              void* d_out, int out_size, void* d_ws, size_t ws_size,
                              hipStream_t stream) {
    const float* Q = (const float*)d_in[0];
    const float* K = (const float*)d_in[1];
    const float* V = (const float*)d_in[2];
    const float* W = (const float*)d_in[3];
    const float* bo = (const float*)d_in[4];
    float* out = (float*)d_out;

    char* ws = (char*)d_ws;
    unsigned short* Kb  = (unsigned short*)(ws);                 // 8 MB
    unsigned short* Vb  = (unsigned short*)(ws + 8388608);       // 8 MB
    unsigned short* Wb  = (unsigned short*)(ws + 16777216);      // 512 KB
    unsigned short* ObA = (unsigned short*)(ws + 17301504);      // 8 MB

    prep_kernel<<<2176, 256, 0, stream>>>(K, V, W, Kb, Vb, Wb);
    attn_kernel<<<dim3(64, 16), 256, 0, stream>>>(Q, Kb, Vb, ObA);
    proj_kernel<<<dim3(64, 8), 256, 0, stream>>>(ObA, Wb, bo, out);
}

// Round 12
// 194.886 us; speedup vs baseline: 1.7295x; 1.7295x over previous
//
#include <hip/hip_runtime.h>
#include <hip/hip_bf16.h>

#define Bn 2
#define Sn 4096
#define Dn 512
#define Hn 8

typedef _Float16 f16x8 __attribute__((ext_vector_type(8)));
typedef __fp16 fp16x2 __attribute__((ext_vector_type(2)));
typedef float f32x16 __attribute__((ext_vector_type(16)));
typedef unsigned uint2v __attribute__((ext_vector_type(2)));

#if __has_builtin(__builtin_amdgcn_global_load_lds)
#define HAS_GLL 1
typedef const __attribute__((address_space(1))) unsigned int* gas1_t;
typedef __attribute__((address_space(3))) unsigned int* las3_t;
// async 16B/lane global->LDS: LDS dst = uniform base + lane*16
static __device__ __forceinline__ void ld_lds16(const void* g, void* l) {
    __builtin_amdgcn_global_load_lds((gas1_t)g, (las3_t)l, 16, 0, 0);
}
#else
#define HAS_GLL 0
#endif

// pack two f32 -> two f16 in one dword (v_cvt_pkrtz_f16_f32, 1 VALU op)
static __device__ __forceinline__ unsigned pkh(float a, float b) {
    union { fp16x2 h; unsigned u; } r;
    r.h = __builtin_amdgcn_cvt_pkrtz(a, b);
    return r.u;
}

// C-layout group pair -> A/B-fragment (K=16 shapes) via lane^32 exchange.
static __device__ __forceinline__ f16x8 xchg2(unsigned g0x, unsigned g0y,
                                              unsigned g1x, unsigned g1y, int hi) {
    union { unsigned u[4]; f16x8 v; } f;
#if __has_builtin(__builtin_amdgcn_permlane32_swap)
    uint2v rx = __builtin_amdgcn_permlane32_swap(g0x, g1x, false, false);
    uint2v ry = __builtin_amdgcn_permlane32_swap(g0y, g1y, false, false);
    f.u[0] = rx.x; f.u[1] = ry.x; f.u[2] = rx.y; f.u[3] = ry.y;
#else
    int sx = hi ? (int)g0x : (int)g1x;
    int sy = hi ? (int)g0y : (int)g1y;
    int rx = __shfl_xor(sx, 32);
    int ry = __shfl_xor(sy, 32);
    unsigned ox = hi ? g1x : g0x;
    unsigned oy = hi ? g1y : g0y;
    f.u[0] = hi ? (unsigned)rx : ox;
    f.u[1] = hi ? (unsigned)ry : oy;
    f.u[2] = hi ? ox : (unsigned)rx;
    f.u[3] = hi ? oy : (unsigned)ry;
#endif
    return f.v;
}

// ---------- unified prepass: K,V,W fp32 -> fragment-ordered f16 ----------
__global__ __launch_bounds__(256) void prep_kernel(
    const float* __restrict__ K, const float* __restrict__ V, const float* __restrict__ W,
    unsigned short* __restrict__ Kb, unsigned short* __restrict__ Vb,
    unsigned short* __restrict__ Wb) {
    const int vb = blockIdx.x;
    const int tid = threadIdx.x;
    if (vb < 1024) {
        const int kt = vb & 63, bh = vb >> 6;
        const int b = bh >> 3, h = bh & 7;
        unsigned short* dst = Kb + ((size_t)bh * 64 + kt) * 4096;
#pragma unroll
        for (int i = 0; i < 2; ++i) {
            int c = tid + i * 256;
            int f = c >> 6, ln = c & 63;
            int ktile = f >> 2, ks = f & 3;
            int row = ktile * 32 + (ln & 31);
            int dk = ks * 16 + (ln >> 5) * 8;
            const float* src = K + ((size_t)(b * Sn + kt * 64 + row)) * Dn + h * 64 + dk;
            float4 a0 = *(const float4*)src;
            float4 a1 = *(const float4*)(src + 4);
            uint4 o;
            o.x = pkh(a0.x, a0.y); o.y = pkh(a0.z, a0.w);
            o.z = pkh(a1.x, a1.y); o.w = pkh(a1.z, a1.w);
            *(uint4*)(dst + c * 8) = o;
        }
    } else if (vb < 2048) {
        const int u = vb - 1024;
        const int kt = u & 63, bh = u >> 6;
        const int b = bh >> 3, h = bh & 7;
        unsigned short* dst = Vb + ((size_t)bh * 64 + kt) * 4096;
#pragma unroll
        for (int i = 0; i < 2; ++i) {
            int c = tid + i * 256;
            int f = c >> 6, ln = c & 63;
            int dt = f >> 2, ks = f & 3;
            int dk = dt * 32 + (ln & 31);
            int key0 = ks * 16 + (ln >> 5) * 8;
            const float* src = V + ((size_t)(b * Sn + kt * 64 + key0)) * Dn + h * 64 + dk;
            uint4 o;
            o.x = pkh(src[0 * Dn], src[1 * Dn]);
            o.y = pkh(src[2 * Dn], src[3 * Dn]);
            o.z = pkh(src[4 * Dn], src[5 * Dn]);
            o.w = pkh(src[6 * Dn], src[7 * Dn]);
            *(uint4*)(dst + c * 8) = o;
        }
    } else {
        int c = (vb - 2048) * 256 + tid;
        int ln = c & 63, f = c >> 6;
        int ntile = f >> 5, ks = f & 31;
        int n = ntile * 32 + (ln & 31);
        int k0 = ks * 16 + (ln >> 5) * 8;
        uint4 o;
        o.x = pkh(W[(size_t)(k0 + 0) * Dn + n], W[(size_t)(k0 + 1) * Dn + n]);
        o.y = pkh(W[(size_t)(k0 + 2) * Dn + n], W[(size_t)(k0 + 3) * Dn + n]);
        o.z = pkh(W[(size_t)(k0 + 4) * Dn + n], W[(size_t)(k0 + 5) * Dn + n]);
        o.w = pkh(W[(size_t)(k0 + 6) * Dn + n], W[(size_t)(k0 + 7) * Dn + n]);
        *(uint4*)(Wb + c * 8) = o;
    }
}

// ---------- flash attention: BARRIER-FREE main loop (private per-wave LDS) ----------
// R11 geometry, VGPR cap corrected. Empirical hipcc rule (6 data points,
// R0/R6/R7/R8/R9/R11): __launch_bounds__(_,4) caps VGPR at 64 (any block
// size); (_,2) caps at >=128. This working set needs ~116 (R7). R11's (256,4)
// spilled (VGPR=64, WRITE 260MB, FETCH 637MB). launch_bounds constrains only
// the compiler; HW still schedules 4 waves/SIMD at 116 VGPR (4x116=464<=512)
// and 4 blocks/CU (4x32KB=128<=160KB LDS). Design: vmcnt is PER-WAVE, so a
// wave staging its OWN 8KB LDS slice via global_load_lds needs only
// s_waitcnt vmcnt(0) - zero main-loop barriers. 1024 blocks x 4 waves; wave
// kg: 64 q-rows x private 1024-key quarter, 32 iters x 32-key chunks,
// 16 MFMA / 8KB per iter. 4 phase-free waves/SIMD -> cross-wave
// MFMA/VALU/vmcnt overlap. Barriers only in kg-reduce epilogue. XCD swizzle:
// 2 bh/XCD -> K/V L2-resident.
__global__ __launch_bounds__(256, 2) void attn_kernel(
    const float* __restrict__ Q,
    const unsigned short* __restrict__ Kb,
    const unsigned short* __restrict__ Vb,
    unsigned short* __restrict__ ObA) {   // [gmtile 256][ksg 32][lane 64][8]
    // [wave 4][ K 4 frags | V 4 frags ] x 512 ushorts = 32 KB
    // epilogue reuse: 6144 floats oacc partials + 192 floats l = 25344 B
    __shared__ __align__(16) unsigned short KV[16384];

    // XCD-aware remap: id%8 -> XCD (round-robin dispatch); 2 bh per XCD residue
    const int id = blockIdx.x + (blockIdx.y << 6);
    const int qt = (id >> 3) & 63;                  // 64-row q-tile
    const int bh = (id & 7) + ((id >> 9) << 3);
    const int b = bh >> 3, h = bh & 7;
    const int tid = threadIdx.x;
    const int kg = tid >> 6;       // key quarter 0..3 (= wave id)
    const int lane = tid & 63;
    const int q = lane & 31;
    const int hi = lane >> 5;
    const float cexp = 0.18033688f;  // (1/sqrt(64)) * log2(e), folded into Q

    // Q B-frags for two q-tiles: rows qt*64 + t*32 + q
    f16x8 qf0[4], qf1[4];
    {
        const float* qp0 = Q + ((size_t)(b * Sn + qt * 64 + q)) * Dn + h * 64 + hi * 8;
        const float* qp1 = qp0 + (size_t)32 * Dn;
#pragma unroll
        for (int ks = 0; ks < 4; ++ks) {
            float4 a0 = *(const float4*)(qp0 + ks * 16);
            float4 a1 = *(const float4*)(qp0 + ks * 16 + 4);
            union { unsigned u[4]; f16x8 v; } f;
            f.u[0] = pkh(a0.x * cexp, a0.y * cexp);
            f.u[1] = pkh(a0.z * cexp, a0.w * cexp);
            f.u[2] = pkh(a1.x * cexp, a1.y * cexp);
            f.u[3] = pkh(a1.z * cexp, a1.w * cexp);
            qf0[ks] = f.v;
            a0 = *(const float4*)(qp1 + ks * 16);
            a1 = *(const float4*)(qp1 + ks * 16 + 4);
            f.u[0] = pkh(a0.x * cexp, a0.y * cexp);
            f.u[1] = pkh(a0.z * cexp, a0.w * cexp);
            f.u[2] = pkh(a1.x * cexp, a1.y * cexp);
            f.u[3] = pkh(a1.z * cexp, a1.w * cexp);
            qf1[ks] = f.v;
        }
    }

    f32x16 zf;
#pragma unroll
    for (int r = 0; r < 16; ++r) zf[r] = 0.f;
    f32x16 oacc[2][2];  // [q-tile t][d-tile dt]
    oacc[0][0] = zf; oacc[0][1] = zf; oacc[1][0] = zf; oacc[1][1] = zf;
    float l0_ = 0.f, l1_ = 0.f;

    const size_t bhbase = (size_t)bh * 64 * 4096;  // ushorts
    const unsigned short* kB = Kb + bhbase;
    const unsigned short* vB = Vb + bhbase;
    unsigned short* const lb = &KV[kg * 4096];     // private 8KB slice

    for (int it = 0; it < 32; ++it) {
        // stage my 32-key chunk: keys kg*1024 + it*32 .. +31
        const int t64 = kg * 16 + (it >> 1);
        const int lohi = it & 1;
        {
            const unsigned short* ks_ = kB + (size_t)t64 * 4096 + lohi * 2048 + lane * 8;
            const unsigned short* vs_ = vB + (size_t)t64 * 4096 + lohi * 1024 + lane * 8;
#if HAS_GLL
            ld_lds16(ks_, lb);          ld_lds16(ks_ + 512, lb + 512);
            ld_lds16(ks_ + 1024, lb + 1024); ld_lds16(ks_ + 1536, lb + 1536);
            ld_lds16(vs_, lb + 2048);   ld_lds16(vs_ + 512, lb + 2560);
            ld_lds16(vs_ + 2048, lb + 3072); ld_lds16(vs_ + 2560, lb + 3584);
            // per-wave completion fence: my loads only (vmcnt is wave-local) - NO barrier
            asm volatile("s_waitcnt vmcnt(0)" ::: "memory");
#else
            uint4 a0 = *(const uint4*)(ks_);        uint4 a1 = *(const uint4*)(ks_ + 512);
            uint4 a2 = *(const uint4*)(ks_ + 1024); uint4 a3 = *(const uint4*)(ks_ + 1536);
            uint4 b0 = *(const uint4*)(vs_);        uint4 b1 = *(const uint4*)(vs_ + 512);
            uint4 b2 = *(const uint4*)(vs_ + 2048); uint4 b3 = *(const uint4*)(vs_ + 2560);
            *(uint4*)&lb[lane * 8] = a0;        *(uint4*)&lb[512 + lane * 8] = a1;
            *(uint4*)&lb[1024 + lane * 8] = a2; *(uint4*)&lb[1536 + lane * 8] = a3;
            *(uint4*)&lb[2048 + lane * 8] = b0; *(uint4*)&lb[2560 + lane * 8] = b1;
            *(uint4*)&lb[3072 + lane * 8] = b2; *(uint4*)&lb[3584 + lane * 8] = b3;
            asm volatile("s_waitcnt lgkmcnt(0)" ::: "memory");
#endif
#if __has_builtin(__builtin_amdgcn_sched_barrier)
            __builtin_amdgcn_sched_barrier(0);
#endif
        }

        // QK: one K-frag read feeds both q-tiles' MFMAs (32-key tile)
        f32x16 sa0, sa1;
        {
            f16x8 kf = *(const f16x8*)&lb[0 * 512 + lane * 8];
            sa0 = __builtin_amdgcn_mfma_f32_32x32x16_f16(kf, qf0[0], zf, 0, 0, 0);
            sa1 = __builtin_amdgcn_mfma_f32_32x32x16_f16(kf, qf1[0], zf, 0, 0, 0);
#pragma unroll
            for (int ks = 1; ks < 4; ++ks) {
                kf = *(const f16x8*)&lb[ks * 512 + lane * 8];
                sa0 = __builtin_amdgcn_mfma_f32_32x32x16_f16(kf, qf0[ks], sa0, 0, 0, 0);
                sa1 = __builtin_amdgcn_mfma_f32_32x32x16_f16(kf, qf1[ks], sa1, 0, 0, 0);
            }
        }
        // exp2 fused with f16 pack (16 packed dwords live, not 32 floats)
        unsigned u0[8], u1[8];
        float s0 = 0.f, s1 = 0.f;
#pragma unroll
        for (int j = 0; j < 8; ++j) {
            float ea = __builtin_amdgcn_exp2f(sa0[2 * j]);
            float eb = __builtin_amdgcn_exp2f(sa0[2 * j + 1]);
            s0 += ea + eb;
            u0[j] = pkh(ea, eb);
        }
#pragma unroll
        for (int j = 0; j < 8; ++j) {
            float ea = __builtin_amdgcn_exp2f(sa1[2 * j]);
            float eb = __builtin_amdgcn_exp2f(sa1[2 * j + 1]);
            s1 += ea + eb;
            u1[j] = pkh(ea, eb);
        }
        l0_ += s0; l1_ += s1;

        // PV: one V-frag pair feeds both q-tiles (2 k-slots of 16 keys)
#pragma unroll
        for (int ks2 = 0; ks2 < 2; ++ks2) {
            f16x8 pb0 = xchg2(u0[4 * ks2 + 0], u0[4 * ks2 + 1], u0[4 * ks2 + 2], u0[4 * ks2 + 3], hi);
            f16x8 pb1 = xchg2(u1[4 * ks2 + 0], u1[4 * ks2 + 1], u1[4 * ks2 + 2], u1[4 * ks2 + 3], hi);
            f16x8 va0 = *(const f16x8*)&lb[2048 + ks2 * 512 + lane * 8];
            f16x8 va1 = *(const f16x8*)&lb[3072 + ks2 * 512 + lane * 8];
            oacc[0][0] = __builtin_amdgcn_mfma_f32_32x32x16_f16(va0, pb0, oacc[0][0], 0, 0, 0);
            oacc[0][1] = __builtin_amdgcn_mfma_f32_32x32x16_f16(va1, pb0, oacc[0][1], 0, 0, 0);
            oacc[1][0] = __builtin_amdgcn_mfma_f32_32x32x16_f16(va0, pb1, oacc[1][0], 0, 0, 0);
            oacc[1][1] = __builtin_amdgcn_mfma_f32_32x32x16_f16(va1, pb1, oacc[1][1], 0, 0, 0);
        }
    }

    // 4-way kg reduction, 2 phases (one per q-tile t). Per phase: kg1..3 write
    // (3 regions x 2048 floats = 24KB) + l (192 floats); kg0 accumulates.
    __syncthreads();
    float* red = (float*)KV;
#pragma unroll
    for (int t = 0; t < 2; ++t) {
        if (kg != 0) {
            float* rp = red + (kg - 1) * 2048;
#pragma unroll
            for (int dt = 0; dt < 2; ++dt)
#pragma unroll
                for (int g = 0; g < 4; ++g) {
                    float4 v;
                    v.x = oacc[t][dt][g * 4 + 0];
                    v.y = oacc[t][dt][g * 4 + 1];
                    v.z = oacc[t][dt][g * 4 + 2];
                    v.w = oacc[t][dt][g * 4 + 3];
                    *(float4*)&rp[(dt * 4 + g) * 256 + lane * 4] = v;
                }
            red[6144 + (kg - 1) * 64 + lane] = t ? l1_ : l0_;
        }
        __syncthreads();
        if (kg == 0) {
#pragma unroll
            for (int slot = 0; slot < 3; ++slot) {
                float* rp = red + slot * 2048;
#pragma unroll
                for (int dt = 0; dt < 2; ++dt)
#pragma unroll
                    for (int g = 0; g < 4; ++g) {
                        float4 v = *(const float4*)&rp[(dt * 4 + g) * 256 + lane * 4];
                        oacc[t][dt][g * 4 + 0] += v.x;
                        oacc[t][dt][g * 4 + 1] += v.y;
                        oacc[t][dt][g * 4 + 2] += v.z;
                        oacc[t][dt][g * 4 + 3] += v.w;
                    }
                float addl = red[6144 + slot * 64 + lane];
                if (t) l1_ += addl; else l0_ += addl;
            }
        }
        __syncthreads();
    }

    if (kg == 0) {
        l0_ += __shfl_xor(l0_, 32);
        l1_ += __shfl_xor(l1_, 32);
#pragma unroll
        for (int t = 0; t < 2; ++t) {
            const float li = 1.f / (t ? l1_ : l0_);
            const int gm = b * 128 + qt * 2 + t;
#pragma unroll
            for (int ksg = 0; ksg < 4; ++ksg) {
                const int dt = ksg >> 1, k2 = ksg & 1;
                unsigned g0x = pkh(oacc[t][dt][8 * k2 + 0] * li, oacc[t][dt][8 * k2 + 1] * li);
                unsigned g0y = pkh(oacc[t][dt][8 * k2 + 2] * li, oacc[t][dt][8 * k2 + 3] * li);
                unsigned g1x = pkh(oacc[t][dt][8 * k2 + 4] * li, oacc[t][dt][8 * k2 + 5] * li);
                unsigned g1y = pkh(oacc[t][dt][8 * k2 + 6] * li, oacc[t][dt][8 * k2 + 7] * li);
                f16x8 frag = xchg2(g0x, g0y, g1x, g1y, hi);
                union { f16x8 v; uint4 u; } fu; fu.v = frag;
                *(uint4*)&ObA[((size_t)(gm * 32 + h * 4 + ksg) * 64 + lane) * 8] = fu.u;
            }
        }
    }
}

// ---------- projection GEMM: out = A @ W + b (A,W fragment-ordered f16) ----------
__global__ __launch_bounds__(256) void proj_kernel(
    const unsigned short* __restrict__ ObA,  // [256][32][64][8]
    const unsigned short* __restrict__ Wb,   // [16][32][64][8]
    const float* __restrict__ bias,
    float* __restrict__ out) {
    __shared__ __align__(16) unsigned short Ash[8192];
    __shared__ __align__(16) unsigned short Wsh[4096];

    const int mt = blockIdx.x;
    const int nt = blockIdx.y;
    const int tid = threadIdx.x;
    const int w = tid >> 6;
    const int lane = tid & 63;
    const int q = lane & 31;
    const int hi = lane >> 5;

    f32x16 acc[2];
#pragma unroll
    for (int t = 0; t < 2; ++t)
#pragma unroll
        for (int r = 0; r < 16; ++r) acc[t][r] = 0.f;

    for (int kt = 0; kt < 8; ++kt) {
        __syncthreads();
#pragma unroll
        for (int i = 0; i < 4; ++i) {
            int ci = (tid >> 6) + i * 4;
            int ml = ci >> 2, ksl = ci & 3;
            *(uint4*)&Ash[ci * 512 + lane * 8] =
                *(const uint4*)(ObA + (((size_t)(mt * 4 + ml) * 32 + kt * 4 + ksl) * 64 + lane) * 8);
        }
#pragma unroll
        for (int i = 0; i < 2; ++i) {
            int ci = (tid >> 6) + i * 4;
            int ntl = ci >> 2, ksl = ci & 3;
            *(uint4*)&Wsh[ci * 512 + lane * 8] =
                *(const uint4*)(Wb + (((size_t)(nt * 2 + ntl) * 32 + kt * 4 + ksl) * 64 + lane) * 8);
        }
        __syncthreads();

#pragma unroll
        for (int ks = 0; ks < 4; ++ks) {
            f16x8 a  = *(const f16x8*)&Ash[(w * 4 + ks) * 512 + lane * 8];
            f16x8 b0 = *(const f16x8*)&Wsh[(0 * 4 + ks) * 512 + lane * 8];
            f16x8 b1 = *(const f16x8*)&Wsh[(4 + ks) * 512 + lane * 8];
            acc[0] = __builtin_amdgcn_mfma_f32_32x32x16_f16(a, b0, acc[0], 0, 0, 0);
            acc[1] = __builtin_amdgcn_mfma_f32_32x32x16_f16(a, b1, acc[1], 0, 0, 0);
        }
    }

#pragma unroll
    for (int ntl = 0; ntl < 2; ++ntl) {
        int col = nt * 64 + ntl * 32 + q;
        float bv = bias[col];
#pragma unroll
        for (int reg = 0; reg < 16; ++reg) {
            int row = mt * 128 + w * 32 + (reg & 3) + 8 * (reg >> 2) + 4 * hi;
            out[(size_t)row * Dn + col] = acc[ntl][reg] + bv;
        }
    }
}

extern "C" void kernel_launch(void* const* d_in, const int* in_sizes, int n_in,
                              void* d_out, int out_size, void* d_ws, size_t ws_size,
                              hipStream_t stream) {
    const float* Q = (const float*)d_in[0];
    const float* K = (const float*)d_in[1];
    const float* V = (const float*)d_in[2];
    const float* W = (const float*)d_in[3];
    const float* bo = (const float*)d_in[4];
    float* out = (float*)d_out;

    char* ws = (char*)d_ws;
    unsigned short* Kb  = (unsigned short*)(ws);                 // 8 MB
    unsigned short* Vb  = (unsigned short*)(ws + 8388608);       // 8 MB
    unsigned short* Wb  = (unsigned short*)(ws + 16777216);      // 512 KB
    unsigned short* ObA = (unsigned short*)(ws + 17301504);      // 8 MB

    prep_kernel<<<2176, 256, 0, stream>>>(K, V, W, Kb, Vb, Wb);
    attn_kernel<<<dim3(64, 16), 256, 0, stream>>>(Q, Kb, Vb, ObA);
    proj_kernel<<<dim3(64, 8), 256, 0, stream>>>(ObA, Wb, bo, out);
}

// Round 13
// 190.253 us; speedup vs baseline: 1.7716x; 1.0244x over previous
//
#include <hip/hip_runtime.h>
#include <hip/hip_bf16.h>

#define Bn 2
#define Sn 4096
#define Dn 512
#define Hn 8

typedef _Float16 f16x8 __attribute__((ext_vector_type(8)));
typedef __fp16 fp16x2 __attribute__((ext_vector_type(2)));
typedef float f32x16 __attribute__((ext_vector_type(16)));
typedef unsigned uint2v __attribute__((ext_vector_type(2)));

#if __has_builtin(__builtin_amdgcn_global_load_lds)
#define HAS_GLL 1
typedef const __attribute__((address_space(1))) unsigned int* gas1_t;
typedef __attribute__((address_space(3))) unsigned int* las3_t;
// async 16B/lane global->LDS: LDS dst = uniform base + lane*16
static __device__ __forceinline__ void ld_lds16(const void* g, void* l) {
    __builtin_amdgcn_global_load_lds((gas1_t)g, (las3_t)l, 16, 0, 0);
}
#else
#define HAS_GLL 0
#endif

// pack two f32 -> two f16 in one dword (v_cvt_pkrtz_f16_f32, 1 VALU op)
static __device__ __forceinline__ unsigned pkh(float a, float b) {
    union { fp16x2 h; unsigned u; } r;
    r.h = __builtin_amdgcn_cvt_pkrtz(a, b);
    return r.u;
}

// C-layout group pair -> A/B-fragment (K=16 shapes) via lane^32 exchange.
static __device__ __forceinline__ f16x8 xchg2(unsigned g0x, unsigned g0y,
                                              unsigned g1x, unsigned g1y, int hi) {
    union { unsigned u[4]; f16x8 v; } f;
#if __has_builtin(__builtin_amdgcn_permlane32_swap)
    uint2v rx = __builtin_amdgcn_permlane32_swap(g0x, g1x, false, false);
    uint2v ry = __builtin_amdgcn_permlane32_swap(g0y, g1y, false, false);
    f.u[0] = rx.x; f.u[1] = ry.x; f.u[2] = rx.y; f.u[3] = ry.y;
#else
    int sx = hi ? (int)g0x : (int)g1x;
    int sy = hi ? (int)g0y : (int)g1y;
    int rx = __shfl_xor(sx, 32);
    int ry = __shfl_xor(sy, 32);
    unsigned ox = hi ? g1x : g0x;
    unsigned oy = hi ? g1y : g0y;
    f.u[0] = hi ? (unsigned)rx : ox;
    f.u[1] = hi ? (unsigned)ry : oy;
    f.u[2] = hi ? ox : (unsigned)rx;
    f.u[3] = hi ? oy : (unsigned)ry;
#endif
    return f.v;
}

// ---------- unified prepass: K,V,W fp32 -> fragment-ordered f16 ----------
__global__ __launch_bounds__(256) void prep_kernel(
    const float* __restrict__ K, const float* __restrict__ V, const float* __restrict__ W,
    unsigned short* __restrict__ Kb, unsigned short* __restrict__ Vb,
    unsigned short* __restrict__ Wb) {
    const int vb = blockIdx.x;
    const int tid = threadIdx.x;
    if (vb < 1024) {
        const int kt = vb & 63, bh = vb >> 6;
        const int b = bh >> 3, h = bh & 7;
        unsigned short* dst = Kb + ((size_t)bh * 64 + kt) * 4096;
#pragma unroll
        for (int i = 0; i < 2; ++i) {
            int c = tid + i * 256;
            int f = c >> 6, ln = c & 63;
            int ktile = f >> 2, ks = f & 3;
            int row = ktile * 32 + (ln & 31);
            int dk = ks * 16 + (ln >> 5) * 8;
            const float* src = K + ((size_t)(b * Sn + kt * 64 + row)) * Dn + h * 64 + dk;
            float4 a0 = *(const float4*)src;
            float4 a1 = *(const float4*)(src + 4);
            uint4 o;
            o.x = pkh(a0.x, a0.y); o.y = pkh(a0.z, a0.w);
            o.z = pkh(a1.x, a1.y); o.w = pkh(a1.z, a1.w);
            *(uint4*)(dst + c * 8) = o;
        }
    } else if (vb < 2048) {
        const int u = vb - 1024;
        const int kt = u & 63, bh = u >> 6;
        const int b = bh >> 3, h = bh & 7;
        unsigned short* dst = Vb + ((size_t)bh * 64 + kt) * 4096;
#pragma unroll
        for (int i = 0; i < 2; ++i) {
            int c = tid + i * 256;
            int f = c >> 6, ln = c & 63;
            int dt = f >> 2, ks = f & 3;
            int dk = dt * 32 + (ln & 31);
            int key0 = ks * 16 + (ln >> 5) * 8;
            const float* src = V + ((size_t)(b * Sn + kt * 64 + key0)) * Dn + h * 64 + dk;
            uint4 o;
            o.x = pkh(src[0 * Dn], src[1 * Dn]);
            o.y = pkh(src[2 * Dn], src[3 * Dn]);
            o.z = pkh(src[4 * Dn], src[5 * Dn]);
            o.w = pkh(src[6 * Dn], src[7 * Dn]);
            *(uint4*)(dst + c * 8) = o;
        }
    } else {
        int c = (vb - 2048) * 256 + tid;
        int ln = c & 63, f = c >> 6;
        int ntile = f >> 5, ks = f & 31;
        int n = ntile * 32 + (ln & 31);
        int k0 = ks * 16 + (ln >> 5) * 8;
        uint4 o;
        o.x = pkh(W[(size_t)(k0 + 0) * Dn + n], W[(size_t)(k0 + 1) * Dn + n]);
        o.y = pkh(W[(size_t)(k0 + 2) * Dn + n], W[(size_t)(k0 + 3) * Dn + n]);
        o.z = pkh(W[(size_t)(k0 + 4) * Dn + n], W[(size_t)(k0 + 5) * Dn + n]);
        o.w = pkh(W[(size_t)(k0 + 6) * Dn + n], W[(size_t)(k0 + 7) * Dn + n]);
        *(uint4*)(Wb + c * 8) = o;
    }
}

// ---------- flash attention: barrier-free + per-wave double buffer + counted vmcnt ----------
// R12 post-mortem: barrier-free alone was null because each iter drained
// vmcnt(0) right after issuing its 8 global_load_lds -> full L2->LDS latency
// (~1000cyc) exposed per 32-key tile with only ~2 waves/SIMD to cover it
// (1840 cyc/wave-iter measured vs ~1100 serial-chain estimate). R9 hid the
// latency but paid the barrier convoy; R12 dropped the convoy but un-hid the
// latency - net zero (the 12-round MfmaUtil*dur~3000 invariant).
// R13 = both: private per-wave DOUBLE-buffered slice (2x8KB) + counted
// s_waitcnt vmcnt(8): issue STAGE(it+1) into the other buffer, wait only for
// tile it's 8 loads (it+1's stay in flight across the whole compute phase),
// never drain to 0 until the last tile. Zero barriers in the main loop.
// WAR safe: compute(it-1)'s ds_reads complete (lgkm-waited before its MFMAs)
// before STAGE(it+1) issues. 1024 blocks x 4 waves; wave kg: 64 q-rows x
// private 1024-key quarter, 32 iters x 32-key chunks, 16 MFMA / 8KB per iter.
// LDS 64KB/block. (256,2): VGPR cap 128 (working set ~96). XCD swizzle:
// 2 bh/XCD -> K/V L2-resident.
__global__ __launch_bounds__(256, 2) void attn_kernel(
    const float* __restrict__ Q,
    const unsigned short* __restrict__ Kb,
    const unsigned short* __restrict__ Vb,
    unsigned short* __restrict__ ObA) {   // [gmtile 256][ksg 32][lane 64][8]
    // [wave 4][buf 2][ K 4 frags | V 4 frags ] x 512 ushorts = 64 KB
    // epilogue reuse: 6144 floats oacc partials + 192 floats l = 25344 B
    __shared__ __align__(16) unsigned short KV[32768];

    // XCD-aware remap: id%8 -> XCD (round-robin dispatch); 2 bh per XCD residue
    const int id = blockIdx.x + (blockIdx.y << 6);
    const int qt = (id >> 3) & 63;                  // 64-row q-tile
    const int bh = (id & 7) + ((id >> 9) << 3);
    const int b = bh >> 3, h = bh & 7;
    const int tid = threadIdx.x;
    const int kg = tid >> 6;       // key quarter 0..3 (= wave id)
    const int lane = tid & 63;
    const int q = lane & 31;
    const int hi = lane >> 5;
    const float cexp = 0.18033688f;  // (1/sqrt(64)) * log2(e), folded into Q

    // Q B-frags for two q-tiles: rows qt*64 + t*32 + q
    f16x8 qf0[4], qf1[4];
    {
        const float* qp0 = Q + ((size_t)(b * Sn + qt * 64 + q)) * Dn + h * 64 + hi * 8;
        const float* qp1 = qp0 + (size_t)32 * Dn;
#pragma unroll
        for (int ks = 0; ks < 4; ++ks) {
            float4 a0 = *(const float4*)(qp0 + ks * 16);
            float4 a1 = *(const float4*)(qp0 + ks * 16 + 4);
            union { unsigned u[4]; f16x8 v; } f;
            f.u[0] = pkh(a0.x * cexp, a0.y * cexp);
            f.u[1] = pkh(a0.z * cexp, a0.w * cexp);
            f.u[2] = pkh(a1.x * cexp, a1.y * cexp);
            f.u[3] = pkh(a1.z * cexp, a1.w * cexp);
            qf0[ks] = f.v;
            a0 = *(const float4*)(qp1 + ks * 16);
            a1 = *(const float4*)(qp1 + ks * 16 + 4);
            f.u[0] = pkh(a0.x * cexp, a0.y * cexp);
            f.u[1] = pkh(a0.z * cexp, a0.w * cexp);
            f.u[2] = pkh(a1.x * cexp, a1.y * cexp);
            f.u[3] = pkh(a1.z * cexp, a1.w * cexp);
            qf1[ks] = f.v;
        }
    }

    f32x16 zf;
#pragma unroll
    for (int r = 0; r < 16; ++r) zf[r] = 0.f;
    f32x16 oacc[2][2];  // [q-tile t][d-tile dt]
    oacc[0][0] = zf; oacc[0][1] = zf; oacc[1][0] = zf; oacc[1][1] = zf;
    float l0_ = 0.f, l1_ = 0.f;

    const size_t bhbase = (size_t)bh * 64 * 4096;  // ushorts
    const unsigned short* kB = Kb + bhbase;
    const unsigned short* vB = Vb + bhbase;
    unsigned short* const lb = &KV[kg * 8192];     // private 16KB slice (2 bufs)

    // stage my 32-key chunk for iter itx into buffer bb (8 async loads, NO wait)
#if HAS_GLL
#define STAGE(itx, bb) { \
    const int t64 = kg * 16 + ((itx) >> 1); \
    const int lohi = (itx) & 1; \
    unsigned short* dst = lb + (bb) * 4096; \
    const unsigned short* ks_ = kB + (size_t)t64 * 4096 + lohi * 2048 + lane * 8; \
    const unsigned short* vs_ = vB + (size_t)t64 * 4096 + lohi * 1024 + lane * 8; \
    ld_lds16(ks_, dst);          ld_lds16(ks_ + 512, dst + 512); \
    ld_lds16(ks_ + 1024, dst + 1024); ld_lds16(ks_ + 1536, dst + 1536); \
    ld_lds16(vs_, dst + 2048);   ld_lds16(vs_ + 512, dst + 2560); \
    ld_lds16(vs_ + 2048, dst + 3072); ld_lds16(vs_ + 2560, dst + 3584); }
#else
#define STAGE(itx, bb) { \
    const int t64 = kg * 16 + ((itx) >> 1); \
    const int lohi = (itx) & 1; \
    unsigned short* dst = lb + (bb) * 4096; \
    const unsigned short* ks_ = kB + (size_t)t64 * 4096 + lohi * 2048 + lane * 8; \
    const unsigned short* vs_ = vB + (size_t)t64 * 4096 + lohi * 1024 + lane * 8; \
    uint4 a0 = *(const uint4*)(ks_);        uint4 a1 = *(const uint4*)(ks_ + 512); \
    uint4 a2 = *(const uint4*)(ks_ + 1024); uint4 a3 = *(const uint4*)(ks_ + 1536); \
    uint4 b0 = *(const uint4*)(vs_);        uint4 b1 = *(const uint4*)(vs_ + 512); \
    uint4 b2 = *(const uint4*)(vs_ + 2048); uint4 b3 = *(const uint4*)(vs_ + 2560); \
    *(uint4*)&dst[lane * 8] = a0;        *(uint4*)&dst[512 + lane * 8] = a1; \
    *(uint4*)&dst[1024 + lane * 8] = a2; *(uint4*)&dst[1536 + lane * 8] = a3; \
    *(uint4*)&dst[2048 + lane * 8] = b0; *(uint4*)&dst[2560 + lane * 8] = b1; \
    *(uint4*)&dst[3072 + lane * 8] = b2; *(uint4*)&dst[3584 + lane * 8] = b3; }
#endif

    // one 32-key tile from buffer cb: QK (both q-tiles), exp2+pack, PV
    auto COMPUTE = [&](const unsigned short* cb) {
        f32x16 sa0, sa1;
        {
            f16x8 kf = *(const f16x8*)&cb[0 * 512 + lane * 8];
            sa0 = __builtin_amdgcn_mfma_f32_32x32x16_f16(kf, qf0[0], zf, 0, 0, 0);
            sa1 = __builtin_amdgcn_mfma_f32_32x32x16_f16(kf, qf1[0], zf, 0, 0, 0);
#pragma unroll
            for (int ks = 1; ks < 4; ++ks) {
                kf = *(const f16x8*)&cb[ks * 512 + lane * 8];
                sa0 = __builtin_amdgcn_mfma_f32_32x32x16_f16(kf, qf0[ks], sa0, 0, 0, 0);
                sa1 = __builtin_amdgcn_mfma_f32_32x32x16_f16(kf, qf1[ks], sa1, 0, 0, 0);
            }
        }
        unsigned u0[8], u1[8];
        float s0 = 0.f, s1 = 0.f;
#pragma unroll
        for (int j = 0; j < 8; ++j) {
            float ea = __builtin_amdgcn_exp2f(sa0[2 * j]);
            float eb = __builtin_amdgcn_exp2f(sa0[2 * j + 1]);
            s0 += ea + eb;
            u0[j] = pkh(ea, eb);
        }
#pragma unroll
        for (int j = 0; j < 8; ++j) {
            float ea = __builtin_amdgcn_exp2f(sa1[2 * j]);
            float eb = __builtin_amdgcn_exp2f(sa1[2 * j + 1]);
            s1 += ea + eb;
            u1[j] = pkh(ea, eb);
        }
        l0_ += s0; l1_ += s1;
#pragma unroll
        for (int ks2 = 0; ks2 < 2; ++ks2) {
            f16x8 pb0 = xchg2(u0[4 * ks2 + 0], u0[4 * ks2 + 1], u0[4 * ks2 + 2], u0[4 * ks2 + 3], hi);
            f16x8 pb1 = xchg2(u1[4 * ks2 + 0], u1[4 * ks2 + 1], u1[4 * ks2 + 2], u1[4 * ks2 + 3], hi);
            f16x8 va0 = *(const f16x8*)&cb[2048 + ks2 * 512 + lane * 8];
            f16x8 va1 = *(const f16x8*)&cb[3072 + ks2 * 512 + lane * 8];
            oacc[0][0] = __builtin_amdgcn_mfma_f32_32x32x16_f16(va0, pb0, oacc[0][0], 0, 0, 0);
            oacc[0][1] = __builtin_amdgcn_mfma_f32_32x32x16_f16(va1, pb0, oacc[0][1], 0, 0, 0);
            oacc[1][0] = __builtin_amdgcn_mfma_f32_32x32x16_f16(va0, pb1, oacc[1][0], 0, 0, 0);
            oacc[1][1] = __builtin_amdgcn_mfma_f32_32x32x16_f16(va1, pb1, oacc[1][1], 0, 0, 0);
        }
    };

    STAGE(0, 0);
    for (int it = 0; it < 31; ++it) {
        STAGE(it + 1, (it + 1) & 1);   // 8 loads for it+1 stay in flight
#if HAS_GLL
        // wait for tile it's 8 loads only (vmcnt counts this wave's VMEM ops;
        // the 8 newest - tile it+1's - remain outstanding through compute)
        asm volatile("s_waitcnt vmcnt(8)" ::: "memory");
#else
        asm volatile("s_waitcnt lgkmcnt(0)" ::: "memory");
#endif
#if __has_builtin(__builtin_amdgcn_sched_barrier)
        __builtin_amdgcn_sched_barrier(0);
#endif
        COMPUTE(lb + (it & 1) * 4096);
    }
    // last tile: drain everything
    asm volatile("s_waitcnt vmcnt(0) lgkmcnt(0)" ::: "memory");
#if __has_builtin(__builtin_amdgcn_sched_barrier)
    __builtin_amdgcn_sched_barrier(0);
#endif
    COMPUTE(lb + (31 & 1) * 4096);

    // 4-way kg reduction, 2 phases (one per q-tile t). Per phase: kg1..3 write
    // (3 regions x 2048 floats = 24KB) + l (192 floats); kg0 accumulates.
    __syncthreads();
    float* red = (float*)KV;
#pragma unroll
    for (int t = 0; t < 2; ++t) {
        if (kg != 0) {
            float* rp = red + (kg - 1) * 2048;
#pragma unroll
            for (int dt = 0; dt < 2; ++dt)
#pragma unroll
                for (int g = 0; g < 4; ++g) {
                    float4 v;
                    v.x = oacc[t][dt][g * 4 + 0];
                    v.y = oacc[t][dt][g * 4 + 1];
                    v.z = oacc[t][dt][g * 4 + 2];
                    v.w = oacc[t][dt][g * 4 + 3];
                    *(float4*)&rp[(dt * 4 + g) * 256 + lane * 4] = v;
                }
            red[6144 + (kg - 1) * 64 + lane] = t ? l1_ : l0_;
        }
        __syncthreads();
        if (kg == 0) {
#pragma unroll
            for (int slot = 0; slot < 3; ++slot) {
                float* rp = red + slot * 2048;
#pragma unroll
                for (int dt = 0; dt < 2; ++dt)
#pragma unroll
                    for (int g = 0; g < 4; ++g) {
                        float4 v = *(const float4*)&rp[(dt * 4 + g) * 256 + lane * 4];
                        oacc[t][dt][g * 4 + 0] += v.x;
                        oacc[t][dt][g * 4 + 1] += v.y;
                        oacc[t][dt][g * 4 + 2] += v.z;
                        oacc[t][dt][g * 4 + 3] += v.w;
                    }
                float addl = red[6144 + slot * 64 + lane];
                if (t) l1_ += addl; else l0_ += addl;
            }
        }
        __syncthreads();
    }

    if (kg == 0) {
        l0_ += __shfl_xor(l0_, 32);
        l1_ += __shfl_xor(l1_, 32);
#pragma unroll
        for (int t = 0; t < 2; ++t) {
            const float li = 1.f / (t ? l1_ : l0_);
            const int gm = b * 128 + qt * 2 + t;
#pragma unroll
            for (int ksg = 0; ksg < 4; ++ksg) {
                const int dt = ksg >> 1, k2 = ksg & 1;
                unsigned g0x = pkh(oacc[t][dt][8 * k2 + 0] * li, oacc[t][dt][8 * k2 + 1] * li);
                unsigned g0y = pkh(oacc[t][dt][8 * k2 + 2] * li, oacc[t][dt][8 * k2 + 3] * li);
                unsigned g1x = pkh(oacc[t][dt][8 * k2 + 4] * li, oacc[t][dt][8 * k2 + 5] * li);
                unsigned g1y = pkh(oacc[t][dt][8 * k2 + 6] * li, oacc[t][dt][8 * k2 + 7] * li);
                f16x8 frag = xchg2(g0x, g0y, g1x, g1y, hi);
                union { f16x8 v; uint4 u; } fu; fu.v = frag;
                *(uint4*)&ObA[((size_t)(gm * 32 + h * 4 + ksg) * 64 + lane) * 8] = fu.u;
            }
        }
    }
}

// ---------- projection GEMM: out = A @ W + b (A,W fragment-ordered f16) ----------
__global__ __launch_bounds__(256) void proj_kernel(
    const unsigned short* __restrict__ ObA,  // [256][32][64][8]
    const unsigned short* __restrict__ Wb,   // [16][32][64][8]
    const float* __restrict__ bias,
    float* __restrict__ out) {
    __shared__ __align__(16) unsigned short Ash[8192];
    __shared__ __align__(16) unsigned short Wsh[4096];

    const int mt = blockIdx.x;
    const int nt = blockIdx.y;
    const int tid = threadIdx.x;
    const int w = tid >> 6;
    const int lane = tid & 63;
    const int q = lane & 31;
    const int hi = lane >> 5;

    f32x16 acc[2];
#pragma unroll
    for (int t = 0; t < 2; ++t)
#pragma unroll
        for (int r = 0; r < 16; ++r) acc[t][r] = 0.f;

    for (int kt = 0; kt < 8; ++kt) {
        __syncthreads();
#pragma unroll
        for (int i = 0; i < 4; ++i) {
            int ci = (tid >> 6) + i * 4;
            int ml = ci >> 2, ksl = ci & 3;
            *(uint4*)&Ash[ci * 512 + lane * 8] =
                *(const uint4*)(ObA + (((size_t)(mt * 4 + ml) * 32 + kt * 4 + ksl) * 64 + lane) * 8);
        }
#pragma unroll
        for (int i = 0; i < 2; ++i) {
            int ci = (tid >> 6) + i * 4;
            int ntl = ci >> 2, ksl = ci & 3;
            *(uint4*)&Wsh[ci * 512 + lane * 8] =
                *(const uint4*)(Wb + (((size_t)(nt * 2 + ntl) * 32 + kt * 4 + ksl) * 64 + lane) * 8);
        }
        __syncthreads();

#pragma unroll
        for (int ks = 0; ks < 4; ++ks) {
            f16x8 a  = *(const f16x8*)&Ash[(w * 4 + ks) * 512 + lane * 8];
            f16x8 b0 = *(const f16x8*)&Wsh[(0 * 4 + ks) * 512 + lane * 8];
            f16x8 b1 = *(const f16x8*)&Wsh[(4 + ks) * 512 + lane * 8];
            acc[0] = __builtin_amdgcn_mfma_f32_32x32x16_f16(a, b0, acc[0], 0, 0, 0);
            acc[1] = __builtin_amdgcn_mfma_f32_32x32x16_f16(a, b1, acc[1], 0, 0, 0);
        }
    }

#pragma unroll
    for (int ntl = 0; ntl < 2; ++ntl) {
        int col = nt * 64 + ntl * 32 + q;
        float bv = bias[col];
#pragma unroll
        for (int reg = 0; reg < 16; ++reg) {
            int row = mt * 128 + w * 32 + (reg & 3) + 8 * (reg >> 2) + 4 * hi;
            out[(size_t)row * Dn + col] = acc[ntl][reg] + bv;
        }
    }
}

extern "C" void kernel_launch(void* const* d_in, const int* in_sizes, int n_in,
                              void* d_out, int out_size, void* d_ws, size_t ws_size,
                              hipStream_t stream) {
    const float* Q = (const float*)d_in[0];
    const float* K = (const float*)d_in[1];
    const float* V = (const float*)d_in[2];
    const float* W = (const float*)d_in[3];
    const float* bo = (const float*)d_in[4];
    float* out = (float*)d_out;

    char* ws = (char*)d_ws;
    unsigned short* Kb  = (unsigned short*)(ws);                 // 8 MB
    unsigned short* Vb  = (unsigned short*)(ws + 8388608);       // 8 MB
    unsigned short* Wb  = (unsigned short*)(ws + 16777216);      // 512 KB
    unsigned short* ObA = (unsigned short*)(ws + 17301504);      // 8 MB

    prep_kernel<<<2176, 256, 0, stream>>>(K, V, W, Kb, Vb, Wb);
    attn_kernel<<<dim3(64, 16), 256, 0, stream>>>(Q, Kb, Vb, ObA);
    proj_kernel<<<dim3(64, 8), 256, 0, stream>>>(ObA, Wb, bo, out);
}

// Round 14
// 181.697 us; speedup vs baseline: 1.8550x; 1.0471x over previous
//
#include <hip/hip_runtime.h>
#include <hip/hip_bf16.h>

#define Bn 2
#define Sn 4096
#define Dn 512
#define Hn 8

typedef _Float16 f16x8 __attribute__((ext_vector_type(8)));
typedef __fp16 fp16x2 __attribute__((ext_vector_type(2)));
typedef float f32x16 __attribute__((ext_vector_type(16)));
typedef unsigned uint2v __attribute__((ext_vector_type(2)));

#if __has_builtin(__builtin_amdgcn_global_load_lds)
#define HAS_GLL 1
typedef const __attribute__((address_space(1))) unsigned int* gas1_t;
typedef __attribute__((address_space(3))) unsigned int* las3_t;
// async 16B/lane global->LDS: LDS dst = uniform base + lane*16
static __device__ __forceinline__ void ld_lds16(const void* g, void* l) {
    __builtin_amdgcn_global_load_lds((gas1_t)g, (las3_t)l, 16, 0, 0);
}
#else
#define HAS_GLL 0
#endif

// pack two f32 -> two f16 in one dword (v_cvt_pkrtz_f16_f32, 1 VALU op)
static __device__ __forceinline__ unsigned pkh(float a, float b) {
    union { fp16x2 h; unsigned u; } r;
    r.h = __builtin_amdgcn_cvt_pkrtz(a, b);
    return r.u;
}

// C-layout group pair -> A/B-fragment (K=16 shapes) via lane^32 exchange.
static __device__ __forceinline__ f16x8 xchg2(unsigned g0x, unsigned g0y,
                                              unsigned g1x, unsigned g1y, int hi) {
    union { unsigned u[4]; f16x8 v; } f;
#if __has_builtin(__builtin_amdgcn_permlane32_swap)
    uint2v rx = __builtin_amdgcn_permlane32_swap(g0x, g1x, false, false);
    uint2v ry = __builtin_amdgcn_permlane32_swap(g0y, g1y, false, false);
    f.u[0] = rx.x; f.u[1] = ry.x; f.u[2] = rx.y; f.u[3] = ry.y;
#else
    int sx = hi ? (int)g0x : (int)g1x;
    int sy = hi ? (int)g0y : (int)g1y;
    int rx = __shfl_xor(sx, 32);
    int ry = __shfl_xor(sy, 32);
    unsigned ox = hi ? g1x : g0x;
    unsigned oy = hi ? g1y : g0y;
    f.u[0] = hi ? (unsigned)rx : ox;
    f.u[1] = hi ? (unsigned)ry : oy;
    f.u[2] = hi ? ox : (unsigned)rx;
    f.u[3] = hi ? oy : (unsigned)ry;
#endif
    return f.v;
}

// ---------- unified prepass: K,V,W fp32 -> fragment-ordered f16 ----------
// R14 change (only change this round): the K-branch previously read float4
// at 2KB stride per lane (row varies per lane) - maximally uncoalesced,
// 64B fetched per 16B used -> K fetch 16MB inflated to ~64MB. Now: coalesced
// row-major float4 reads -> f16 -> LDS (granule-XOR swizzle (d>>3)^(r&7),
// G4 recipe, so the strided fragment reads don't 32-way bank-conflict) ->
// fragment-ordered reads -> coalesced global writes. Output layout identical.
__global__ __launch_bounds__(256) void prep_kernel(
    const float* __restrict__ K, const float* __restrict__ V, const float* __restrict__ W,
    unsigned short* __restrict__ Kb, unsigned short* __restrict__ Vb,
    unsigned short* __restrict__ Wb) {
    __shared__ __align__(16) unsigned short L[4096];  // 8KB: 64 rows x 64 f16 (swizzled)
    const int vb = blockIdx.x;
    const int tid = threadIdx.x;
    if (vb < 1024) {
        const int kt = vb & 63, bh = vb >> 6;
        const int b = bh >> 3, h = bh & 7;
        unsigned short* dst = Kb + ((size_t)bh * 64 + kt) * 4096;
        const float* src0 = K + ((size_t)(b * Sn + kt * 64)) * Dn + h * 64;
        // phase 1: coalesced read of the 64x64 f32 tile (16 lanes x float4 per row)
#pragma unroll
        for (int p = 0; p < 4; ++p) {
            int u = tid + p * 256;            // 0..1023
            int r = u >> 4;                   // row 0..63
            int dq = (u & 15) * 4;            // dk 0..60 step 4
            float4 a = *(const float4*)(src0 + (size_t)r * Dn + dq);
            unsigned lo = pkh(a.x, a.y), hi2 = pkh(a.z, a.w);
            int g = (dq >> 3) ^ (r & 7);      // swizzled 16B granule
            unsigned short* wp = &L[r * 64 + (g << 3) + (dq & 7)];
            uint2 wv; wv.x = lo; wv.y = hi2;
            *(uint2*)wp = wv;                 // 8B aligned store
        }
        __syncthreads();
        // phase 2: fragment-ordered LDS reads (swizzle-spread rows) + coalesced writes
#pragma unroll
        for (int p = 0; p < 2; ++p) {
            int c = tid + p * 256;            // 0..511
            int f = c >> 6, ln = c & 63;
            int row = (f >> 2) * 32 + (ln & 31);
            int dk0 = (f & 3) * 16 + (ln >> 5) * 8;
            int g = (dk0 >> 3) ^ (row & 7);
            *(uint4*)(dst + c * 8) = *(const uint4*)&L[row * 64 + (g << 3)];
        }
    } else if (vb < 2048) {
        const int u = vb - 1024;
        const int kt = u & 63, bh = u >> 6;
        const int b = bh >> 3, h = bh & 7;
        unsigned short* dst = Vb + ((size_t)bh * 64 + kt) * 4096;
#pragma unroll
        for (int i = 0; i < 2; ++i) {
            int c = tid + i * 256;
            int f = c >> 6, ln = c & 63;
            int dt = f >> 2, ks = f & 3;
            int dk = dt * 32 + (ln & 31);
            int key0 = ks * 16 + (ln >> 5) * 8;
            const float* src = V + ((size_t)(b * Sn + kt * 64 + key0)) * Dn + h * 64 + dk;
            uint4 o;
            o.x = pkh(src[0 * Dn], src[1 * Dn]);
            o.y = pkh(src[2 * Dn], src[3 * Dn]);
            o.z = pkh(src[4 * Dn], src[5 * Dn]);
            o.w = pkh(src[6 * Dn], src[7 * Dn]);
            *(uint4*)(dst + c * 8) = o;
        }
    } else {
        int c = (vb - 2048) * 256 + tid;
        int ln = c & 63, f = c >> 6;
        int ntile = f >> 5, ks = f & 31;
        int n = ntile * 32 + (ln & 31);
        int k0 = ks * 16 + (ln >> 5) * 8;
        uint4 o;
        o.x = pkh(W[(size_t)(k0 + 0) * Dn + n], W[(size_t)(k0 + 1) * Dn + n]);
        o.y = pkh(W[(size_t)(k0 + 2) * Dn + n], W[(size_t)(k0 + 3) * Dn + n]);
        o.z = pkh(W[(size_t)(k0 + 4) * Dn + n], W[(size_t)(k0 + 5) * Dn + n]);
        o.w = pkh(W[(size_t)(k0 + 6) * Dn + n], W[(size_t)(k0 + 7) * Dn + n]);
        *(uint4*)(Wb + c * 8) = o;
    }
}

// ---------- flash attention (champion R0 structure, byte-identical) ----------
// 512 thr = 8 waves: waves 0-3 keys 0..2047, waves 4-7 keys 2048..4095;
// wave pair (w4, w4+4) shares q-tile; pair-reduce via LDS at end.
// Retained after 13 structural A/Bs (barrier-free, counted-vmcnt, K-direct,
// intensity-doubled all <= this): the loop is VALU+MFMA issue-bound; this
// config's 4 waves/SIMD is the best stall-filler measured (84us attn).
__global__ __launch_bounds__(512, 4) void attn_kernel(
    const float* __restrict__ Q,
    const unsigned short* __restrict__ Kb,
    const unsigned short* __restrict__ Vb,
    unsigned short* __restrict__ ObA) {   // [gmtile 256][ksg 32][lane 64][8]
    // double buffer: buf b at b*16384 ushorts; K half at half*4096, V at +8192
    __shared__ __align__(16) unsigned short KV[32768];  // 64 KB

    const int qt = blockIdx.x;
    const int bh = blockIdx.y;
    const int b = bh >> 3, h = bh & 7;
    const int tid = threadIdx.x;
    const int wg = tid >> 6;
    const int half = wg >> 2;
    const int w4 = wg & 3;
    const int lane = tid & 63;
    const int q = lane & 31;
    const int hi = lane >> 5;
    const int q0 = qt * 128 + w4 * 32;
    const float cexp = 0.18033688f;  // (1/sqrt(64)) * log2(e), folded into Q

    // Q B-frags (K=16): col=q, k(dk) = ks*16 + hi*8 + j
    f16x8 qf[4];
    {
        const float* qp = Q + ((size_t)(b * Sn + q0 + q)) * Dn + h * 64 + hi * 8;
#pragma unroll
        for (int ks = 0; ks < 4; ++ks) {
            float4 a0 = *(const float4*)(qp + ks * 16);
            float4 a1 = *(const float4*)(qp + ks * 16 + 4);
            union { unsigned u[4]; f16x8 v; } f;
            f.u[0] = pkh(a0.x * cexp, a0.y * cexp);
            f.u[1] = pkh(a0.z * cexp, a0.w * cexp);
            f.u[2] = pkh(a1.x * cexp, a1.y * cexp);
            f.u[3] = pkh(a1.z * cexp, a1.w * cexp);
            qf[ks] = f.v;
        }
    }

    f32x16 zf;
#pragma unroll
    for (int r = 0; r < 16; ++r) zf[r] = 0.f;
    f32x16 oacc[2];
    oacc[0] = zf; oacc[1] = zf;
    float l_ = 0.f;

    const size_t tbase = ((size_t)bh * 64 + half * 32) * 4096;
    // wave-local staging region: wave w4 covers ushorts [w4*1024, w4*1024+1024) of each tile
    const unsigned short* kgw = Kb + tbase + w4 * 1024;
    const unsigned short* vgw = Vb + tbase + w4 * 1024;
    const int lK = half * 4096 + w4 * 1024;       // ushort offset within a buffer
    const int lV = 8192 + half * 4096 + w4 * 1024;

#if HAS_GLL
#define STAGE(itx, bb) { \
    const unsigned short* ksp = kgw + (size_t)(itx) * 4096 + lane * 8; \
    const unsigned short* vsp = vgw + (size_t)(itx) * 4096 + lane * 8; \
    unsigned short* lk = &KV[(bb) * 16384 + lK]; \
    unsigned short* lv = &KV[(bb) * 16384 + lV]; \
    ld_lds16(ksp, lk); ld_lds16(ksp + 512, lk + 512); \
    ld_lds16(vsp, lv); ld_lds16(vsp + 512, lv + 512); }
    STAGE(0, 0);
#else
    const int th = tid & 255;
#define STAGE(itx, bb) { \
    const unsigned short* ksp = kgw - (size_t)w4 * 1024 + (size_t)(itx) * 4096; \
    const unsigned short* vsp = vgw - (size_t)w4 * 1024 + (size_t)(itx) * 4096; \
    uint4 a0 = *(const uint4*)(ksp + th * 8); \
    uint4 a1 = *(const uint4*)(ksp + 2048 + th * 8); \
    uint4 a2 = *(const uint4*)(vsp + th * 8); \
    uint4 a3 = *(const uint4*)(vsp + 2048 + th * 8); \
    unsigned short* lk = &KV[(bb) * 16384 + half * 4096]; \
    unsigned short* lv = &KV[(bb) * 16384 + 8192 + half * 4096]; \
    *(uint4*)&lk[th * 8] = a0; *(uint4*)&lk[2048 + th * 8] = a1; \
    *(uint4*)&lv[th * 8] = a2; *(uint4*)&lv[2048 + th * 8] = a3; }
    STAGE(0, 0);
#endif

    for (int it = 0; it < 32; ++it) {
        __syncthreads();   // drains staging (vmcnt/lgkm); buf[it&1] complete; prev readers done
        const unsigned short* Kbuf = KV + (it & 1) * 16384 + half * 4096;
        const unsigned short* Vbuf = Kbuf + 8192;
        if (it < 31) STAGE(it + 1, (it + 1) & 1);

        // S^T: both 32-key tiles' chains interleaved (2 independent MFMA chains)
        f32x16 sa0, sa1;
        {
            f16x8 ka = *(const f16x8*)&Kbuf[0 * 512 + lane * 8];
            f16x8 kb = *(const f16x8*)&Kbuf[4 * 512 + lane * 8];
            sa0 = __builtin_amdgcn_mfma_f32_32x32x16_f16(ka, qf[0], zf, 0, 0, 0);
            sa1 = __builtin_amdgcn_mfma_f32_32x32x16_f16(kb, qf[0], zf, 0, 0, 0);
#pragma unroll
            for (int ks = 1; ks < 4; ++ks) {
                ka = *(const f16x8*)&Kbuf[(0 + ks) * 512 + lane * 8];
                kb = *(const f16x8*)&Kbuf[(4 + ks) * 512 + lane * 8];
                sa0 = __builtin_amdgcn_mfma_f32_32x32x16_f16(ka, qf[ks], sa0, 0, 0, 0);
                sa1 = __builtin_amdgcn_mfma_f32_32x32x16_f16(kb, qf[ks], sa1, 0, 0, 0);
            }
        }
        // p = exp2(s); lane-local l
        float e0[16], e1[16];
        float s0 = 0.f, s1 = 0.f;
#pragma unroll
        for (int r = 0; r < 16; ++r) { e0[r] = __builtin_amdgcn_exp2f(sa0[r]); s0 += e0[r]; }
#pragma unroll
        for (int r = 0; r < 16; ++r) { e1[r] = __builtin_amdgcn_exp2f(sa1[r]); s1 += e1[r]; }
        l_ += s0 + s1;

        // O^T += V^T . P^T  (K=16: B-frags from C-groups via permlane32_swap)
#pragma unroll
        for (int kp = 0; kp < 4; ++kp) {
            const float* e = (kp < 2) ? e0 : e1;
            const int s2 = kp & 1;
            unsigned g0x = pkh(e[8 * s2 + 0], e[8 * s2 + 1]);
            unsigned g0y = pkh(e[8 * s2 + 2], e[8 * s2 + 3]);
            unsigned g1x = pkh(e[8 * s2 + 4], e[8 * s2 + 5]);
            unsigned g1y = pkh(e[8 * s2 + 6], e[8 * s2 + 7]);
            f16x8 pb = xchg2(g0x, g0y, g1x, g1y, hi);
            f16x8 va0 = *(const f16x8*)&Vbuf[(0 + kp) * 512 + lane * 8];
            f16x8 va1 = *(const f16x8*)&Vbuf[(4 + kp) * 512 + lane * 8];
            oacc[0] = __builtin_amdgcn_mfma_f32_32x32x16_f16(va0, pb, oacc[0], 0, 0, 0);
            oacc[1] = __builtin_amdgcn_mfma_f32_32x32x16_f16(va1, pb, oacc[1], 0, 0, 0);
        }
    }

    // pair reduction through LDS (reuse KV: rp = 8192 floats, Ls at float ofs 8192)
    __syncthreads();
    float* rp = (float*)KV + w4 * 2048;
    float* Ls = (float*)KV + 8192 + w4 * 64;
    if (half) {
#pragma unroll
        for (int g = 0; g < 8; ++g) {
            float4 v;
            v.x = oacc[g >> 2][(g & 3) * 4 + 0];
            v.y = oacc[g >> 2][(g & 3) * 4 + 1];
            v.z = oacc[g >> 2][(g & 3) * 4 + 2];
            v.w = oacc[g >> 2][(g & 3) * 4 + 3];
            *(float4*)&rp[g * 256 + lane * 4] = v;
        }
        Ls[lane] = l_;
    }
    __syncthreads();
    if (!half) {
#pragma unroll
        for (int g = 0; g < 8; ++g) {
            float4 v = *(const float4*)&rp[g * 256 + lane * 4];
            oacc[g >> 2][(g & 3) * 4 + 0] += v.x;
            oacc[g >> 2][(g & 3) * 4 + 1] += v.y;
            oacc[g >> 2][(g & 3) * 4 + 2] += v.z;
            oacc[g >> 2][(g & 3) * 4 + 3] += v.w;
        }
        l_ += Ls[lane];
        l_ += __shfl_xor(l_, 32);
        const float li = 1.f / l_;
        const int gm = b * 128 + qt * 4 + w4;
#pragma unroll
        for (int ksg = 0; ksg < 4; ++ksg) {
            const int dt = ksg >> 1, k2 = ksg & 1;
            unsigned g0x = pkh(oacc[dt][8 * k2 + 0] * li, oacc[dt][8 * k2 + 1] * li);
            unsigned g0y = pkh(oacc[dt][8 * k2 + 2] * li, oacc[dt][8 * k2 + 3] * li);
            unsigned g1x = pkh(oacc[dt][8 * k2 + 4] * li, oacc[dt][8 * k2 + 5] * li);
            unsigned g1y = pkh(oacc[dt][8 * k2 + 6] * li, oacc[dt][8 * k2 + 7] * li);
            f16x8 frag = xchg2(g0x, g0y, g1x, g1y, hi);
            union { f16x8 v; uint4 u; } fu; fu.v = frag;
            *(uint4*)&ObA[((size_t)(gm * 32 + h * 4 + ksg) * 64 + lane) * 8] = fu.u;
        }
    }
}

// ---------- projection GEMM: out = A @ W + b (A,W fragment-ordered f16) ----------
__global__ __launch_bounds__(256) void proj_kernel(
    const unsigned short* __restrict__ ObA,  // [256][32][64][8]
    const unsigned short* __restrict__ Wb,   // [16][32][64][8]
    const float* __restrict__ bias,
    float* __restrict__ out) {
    __shared__ __align__(16) unsigned short Ash[8192];
    __shared__ __align__(16) unsigned short Wsh[4096];

    const int mt = blockIdx.x;
    const int nt = blockIdx.y;
    const int tid = threadIdx.x;
    const int w = tid >> 6;
    const int lane = tid & 63;
    const int q = lane & 31;
    const int hi = lane >> 5;

    f32x16 acc[2];
#pragma unroll
    for (int t = 0; t < 2; ++t)
#pragma unroll
        for (int r = 0; r < 16; ++r) acc[t][r] = 0.f;

    for (int kt = 0; kt < 8; ++kt) {
        __syncthreads();
#pragma unroll
        for (int i = 0; i < 4; ++i) {
            int ci = (tid >> 6) + i * 4;
            int ml = ci >> 2, ksl = ci & 3;
            *(uint4*)&Ash[ci * 512 + lane * 8] =
                *(const uint4*)(ObA + (((size_t)(mt * 4 + ml) * 32 + kt * 4 + ksl) * 64 + lane) * 8);
        }
#pragma unroll
        for (int i = 0; i < 2; ++i) {
            int ci = (tid >> 6) + i * 4;
            int ntl = ci >> 2, ksl = ci & 3;
            *(uint4*)&Wsh[ci * 512 + lane * 8] =
                *(const uint4*)(Wb + (((size_t)(nt * 2 + ntl) * 32 + kt * 4 + ksl) * 64 + lane) * 8);
        }
        __syncthreads();

#pragma unroll
        for (int ks = 0; ks < 4; ++ks) {
            f16x8 a  = *(const f16x8*)&Ash[(w * 4 + ks) * 512 + lane * 8];
            f16x8 b0 = *(const f16x8*)&Wsh[(0 * 4 + ks) * 512 + lane * 8];
            f16x8 b1 = *(const f16x8*)&Wsh[(4 + ks) * 512 + lane * 8];
            acc[0] = __builtin_amdgcn_mfma_f32_32x32x16_f16(a, b0, acc[0], 0, 0, 0);
            acc[1] = __builtin_amdgcn_mfma_f32_32x32x16_f16(a, b1, acc[1], 0, 0, 0);
        }
    }

#pragma unroll
    for (int ntl = 0; ntl < 2; ++ntl) {
        int col = nt * 64 + ntl * 32 + q;
        float bv = bias[col];
#pragma unroll
        for (int reg = 0; reg < 16; ++reg) {
            int row = mt * 128 + w * 32 + (reg & 3) + 8 * (reg >> 2) + 4 * hi;
            out[(size_t)row * Dn + col] = acc[ntl][reg] + bv;
        }
    }
}

extern "C" void kernel_launch(void* const* d_in, const int* in_sizes, int n_in,
                              void* d_out, int out_size, void* d_ws, size_t ws_size,
                              hipStream_t stream) {
    const float* Q = (const float*)d_in[0];
    const float* K = (const float*)d_in[1];
    const float* V = (const float*)d_in[2];
    const float* W = (const float*)d_in[3];
    const float* bo = (const float*)d_in[4];
    float* out = (float*)d_out;

    char* ws = (char*)d_ws;
    unsigned short* Kb  = (unsigned short*)(ws);                 // 8 MB
    unsigned short* Vb  = (unsigned short*)(ws + 8388608);       // 8 MB
    unsigned short* Wb  = (unsigned short*)(ws + 16777216);      // 512 KB
    unsigned short* ObA = (unsigned short*)(ws + 17301504);      // 8 MB

    prep_kernel<<<2176, 256, 0, stream>>>(K, V, W, Kb, Vb, Wb);
    attn_kernel<<<dim3(32, 16), 512, 0, stream>>>(Q, Kb, Vb, ObA);
    proj_kernel<<<dim3(64, 8), 256, 0, stream>>>(ObA, Wb, bo, out);
}